// Round 10
// baseline (370.808 us; speedup 1.0000x reference)
//
#include <hip/hip_runtime.h>
#include <cstdint>
#include <cstddef>

// ---------------------------------------------------------------------------
// NN_each_LN_exp: 33x33 SAME convs on 32x32 maps = dense 1024x1024 linear
// operators -> f16 MFMA GEMMs with fused epilogues. Row layout r = n*4+k.
// R25 = R24 with the MLP staging bug fixed (BM=32 A-tile = 256 chunks; R24
// staged only 128 -> wm==1 waves read uninit LDS -> NaN). R24's changes:
//  (a) BAND LOAD-BALANCE: co-resident blocks {slot, slot+32, ...} all had
//      the same bx -> a CU ran 4x16 or 4x10 banded K-tiles (23% skew).
//      Flip bx -> 7-bx on odd (slot>>5) quarters: every CU gets
//      {a,7-a,a,7-a} = 52 tiles exactly.
//  (b) epilogue global loads hoisted BEFORE the acc->LDS barrier (T14).
//  (c) MLP retiled BM=32 / 128 blocks.
// Session ledger:
//  - 128x128 tile / 4 waves / pure-async m97 staging: measured optimum
//  - 8-phase 256^2: neutral at K=1024 (R17); chain fusion: regress (R18)
//  - vector epilogues (R19), mask expansion + (256,4) (R20), band (R21)
//  - s-fold (A = NC*s in K-loop): REGRESSION x2 (R16,R22). DO NOT RETRY.
// ---------------------------------------------------------------------------

typedef _Float16 f16;
typedef __attribute__((ext_vector_type(8))) _Float16 f16x8;
typedef __attribute__((ext_vector_type(4))) float f32x4;

#define NB   4096
#define PIX  1024
#define MR   (NB * 4)

__device__ __forceinline__ void gld_lds16(const void* g, void* l) {
    __builtin_amdgcn_global_load_lds(
        (const __attribute__((address_space(1))) void*)g,
        (__attribute__((address_space(3))) void*)l, 16, 0, 0);
}

// conv band: K-tile t (64 inputs = 2 in-rows) vs o-tile starting out-row i0
__device__ __forceinline__ void band_range(int otile, int& t_lo, int& t_hi) {
    int i0 = otile >> 5;
    t_lo = (i0 > 16) ? ((i0 - 16) >> 1) : 0;
    t_hi = (i0 + 19) >> 1;
    if (t_hi > 15) t_hi = 15;
}

// balance flip: co-resident slots differ by 32; band(a)+band(7-a) = 26
__device__ __forceinline__ int bx_balanced(int slot, int nx) {
    int base = slot % nx;
    return ((slot >> 5) & 1) ? (nx - 1 - base) : base;
}

// Merged builds: [0,4096) conv mats, [4096,4608) W1 pad,
// [4608,5632) board transpose + mask expansion (from LDS tile)
__global__ void build_all(const float* __restrict__ we, const float* __restrict__ wn,
                          const float* __restrict__ wn2, const float* __restrict__ wem,
                          const float* __restrict__ W1, const int* __restrict__ dots,
                          f16* __restrict__ Me, f16* __restrict__ Mn,
                          f16* __restrict__ Mn2, f16* __restrict__ Mem,
                          f16* __restrict__ W1b, unsigned char* __restrict__ board,
                          f16* __restrict__ eachF, f16* __restrict__ notmF,
                          f16* __restrict__ emptyF) {
    __shared__ unsigned char tile[64][68];
    int bi = blockIdx.x, t = threadIdx.x;
    if (bi < 4096) {
        int idx = bi * 256 + t;
        int o = idx >> 10, in = idx & 1023;
        int i = o >> 5, j = o & 31, a = in >> 5, b = in & 31;
        int u = a - i + 16, v = b - j + 16;
        bool ok = (u >= 0) && (u < 33) && (v >= 0) && (v < 33);
        int w = u * 33 + v;
        float ve = 0.f, vn = 0.f, vn2 = 0.f, vem = 0.f;
        if (ok) { ve = we[w]; vn = wn[w]; vn2 = wn2[w]; vem = wem[w]; }
        Me[idx]  = (f16)ve;
        Mn[idx]  = (f16)vn;
        Mn2[idx] = (f16)vn2;
        Mem[idx] = (f16)vem;
    } else if (bi < 4608) {
        int idx = (bi - 4096) * 256 + t;
        int j = idx >> 10, i = idx & 1023;
        W1b[idx] = (f16)(j < 100 ? W1[j * 1024 + i] : 0.f);
    } else {
        int bb = bi - 4608;
        int bp = bb & 15, bn = bb >> 4;
        int p0 = bp * 64, n0 = bn * 64;
        int ln = t & 63, lp = t >> 6;
#pragma unroll
        for (int j = 0; j < 16; j++) {
            int p = lp * 16 + j;
            tile[p][ln] = (unsigned char)dots[(size_t)(p0 + p) * 4096 + n0 + ln];
        }
        __syncthreads();
#pragma unroll
        for (int j = 0; j < 16; j++) {
            int n = lp * 16 + j;
            unsigned char c = tile[ln][n];
            size_t nrow = (size_t)(n0 + n);
            board[nrow * 1024 + p0 + ln] = c;
            emptyF[nrow * PIX + p0 + ln] = (c == 0) ? (f16)1.f : (f16)0.f;
            size_t r0 = (nrow * 4) * PIX + p0 + ln;
#pragma unroll
            for (int k = 0; k < 4; k++) {
                unsigned char k1 = (unsigned char)(k + 1);
                eachF[r0 + (size_t)k * PIX] = (c == k1) ? (f16)1.f : (f16)0.f;
                notmF[r0 + (size_t)k * PIX] =
                    (c != 0 && c != k1) ? (f16)1.f : (f16)0.f;
            }
        }
    }
}

// ---------------------------------------------------------------------------
// Generic GEMM body: BM=BN=128, BK=64, 4 waves as 2x2, 16x16x32 MFMA,
// XOR-swizzled chunks, pure-async gld_lds staging, banded K-loop,
// balanced bx. MODE: 0 f16-out; 2 stage1 fused-mk_sa.
// ---------------------------------------------------------------------------
template <int MODE>
__device__ __forceinline__ void run_gemm(
    int bjob, int ypx, int nx, char* smem,
    const f16* __restrict__ X, const f16* __restrict__ B,
    const unsigned char* __restrict__ board, const f16* __restrict__ En,
    const f16* __restrict__ NCs, f16* __restrict__ Lsel,
    f16* __restrict__ Pout, f16* __restrict__ outB, int ldo) {
    char* smB = smem;                              // 16 KB
    char* smA = smem + 16384;

    const int tid = threadIdx.x;
    const int wv = tid >> 6, ln = tid & 63;
    const int wm = wv >> 1, wn_ = wv & 1;
    const int lr = ln & 15, lq = ln >> 4;

    int xcd = bjob & 7, slot = bjob >> 3;
    int bx = bx_balanced(slot, nx);
    int by = xcd * ypx + slot / nx;
    const int rtile = by * 128, otile = bx * 128;

    int t_lo, t_hi;
    band_range(otile, t_lo, t_hi);

    const f32x4 fz = {0.f, 0.f, 0.f, 0.f};
    f32x4 acc[4][4];
#pragma unroll
    for (int i = 0; i < 4; i++)
#pragma unroll
        for (int j = 0; j < 4; j++) acc[i][j] = fz;

    for (int kt = t_lo; kt <= t_hi; kt++) {
        const int kb = kt * 64;
#pragma unroll
        for (int t = 0; t < 4; t++) {
            int c = (wv * 4 + t) * 64 + ln;
            int row = c >> 3, gcol = (c & 7) ^ (row & 7);
            gld_lds16(B + (size_t)(otile + row) * 1024 + kb + gcol * 8, smB + c * 16);
            gld_lds16(X + (size_t)(rtile + row) * 1024 + kb + gcol * 8, smA + c * 16);
        }
        __syncthreads();

#pragma unroll
        for (int kk = 0; kk < 2; kk++) {
            const int oct = kk * 4 + lq;
            f16x8 af[4], bfr[4];
#pragma unroll
            for (int i = 0; i < 4; i++) {
                int rrow = wm * 64 + i * 16 + lr;
                af[i] = *(const f16x8*)(smA + rrow * 128 + (oct ^ (rrow & 7)) * 16);
            }
#pragma unroll
            for (int j = 0; j < 4; j++) {
                int brow = wn_ * 64 + j * 16 + lr;
                bfr[j] = *(const f16x8*)(smB + brow * 128 + (oct ^ (brow & 7)) * 16);
            }
#pragma unroll
            for (int i = 0; i < 4; i++)
#pragma unroll
                for (int j = 0; j < 4; j++)
                    acc[i][j] = __builtin_amdgcn_mfma_f32_16x16x32_f16(
                        af[i], bfr[j], acc[i][j], 0, 0, 0);
        }
        __syncthreads();
    }

    // ---- vectorized epilogue (staging LDS is dead past here) ----
    if constexpr (MODE == 0) {
        f16* sT = (f16*)smem;
#pragma unroll
        for (int i = 0; i < 4; i++) {
            int rb = wm * 64 + i * 16 + lq * 4;
#pragma unroll
            for (int j = 0; j < 4; j++) {
                int col = wn_ * 64 + j * 16 + lr;
                f32x4 a = acc[i][j];
#pragma unroll
                for (int v = 0; v < 4; v++)
                    sT[(rb + v) * 136 + col] = (f16)a[v];
            }
        }
        __syncthreads();
#pragma unroll
        for (int it = 0; it < 8; it++) {
            int row = it * 16 + (tid >> 4), cg = tid & 15;
            f16x8 vv = *(const f16x8*)(sT + row * 136 + cg * 8);
            *(f16x8*)(outB + (size_t)(rtile + row) * ldo + otile + cg * 8) = vv;
        }
    } else {
        // f32 acc halves [64][132]; epilogue loads hoisted above the barrier
        float* sAcc = (float*)smem;
#pragma unroll
        for (int h = 0; h < 2; h++) {
            int cell = tid >> 4, cg = tid & 15;
            int rb = rtile + h * 64 + cell * 4;
            int ngl = rb >> 2;
            int o = otile + cg * 8;
            size_t no = (size_t)ngl * PIX + o;
            size_t r0 = (size_t)rb * PIX + o;
            // issue-early: loads complete during the LDS write + barrier
            uint64_t bb = *(const uint64_t*)(board + no);
            f16x8 en8 = *(const f16x8*)(En + no);
            f16x8 nc0 = *(const f16x8*)(NCs + r0);
            f16x8 nc1 = *(const f16x8*)(NCs + r0 + PIX);
            f16x8 nc2 = *(const f16x8*)(NCs + r0 + 2 * PIX);
            f16x8 nc3 = *(const f16x8*)(NCs + r0 + 3 * PIX);
            if (wm == h) {
#pragma unroll
                for (int i = 0; i < 4; i++) {
                    int lrow = i * 16 + lq * 4;
#pragma unroll
                    for (int j = 0; j < 4; j++) {
                        int col = wn_ * 64 + j * 16 + lr;
                        f32x4 a = acc[i][j];
#pragma unroll
                        for (int v = 0; v < 4; v++)
                            sAcc[(lrow + v) * 132 + col] = a[v];
                    }
                }
            }
            __syncthreads();
            {
                const float* ar = sAcc + cell * 4 * 132 + cg * 8;
                f32x4 arow[4][2];
#pragma unroll
                for (int k = 0; k < 4; k++) {
                    arow[k][0] = *(const f32x4*)(ar + k * 132);
                    arow[k][1] = *(const f32x4*)(ar + k * 132 + 4);
                }
                f16x8 lout, p0, p1, p2, p3;
#pragma unroll
                for (int j2 = 0; j2 < 8; j2++) {
                    int c = (int)((bb >> (8 * j2)) & 0xff);
                    float a0 = arow[0][j2 >> 2][j2 & 3];
                    float a1 = arow[1][j2 >> 2][j2 & 3];
                    float a2 = arow[2][j2 >> 2][j2 & 3];
                    float a3 = arow[3][j2 >> 2][j2 & 3];
                    float asel = (c == 1) ? a0 : (c == 2) ? a1 : (c == 3) ? a2 : a3;
                    float L = 0.f;
                    if (c > 0) {
                        float ncsel = (float)((c == 1) ? nc0[j2] : (c == 2) ? nc1[j2]
                                            : (c == 3) ? nc2[j2] : nc3[j2]);
                        L = asel + (float)en8[j2] - ncsel;
                    }
                    lout[j2] = (f16)L;
                    f16 s = (f16)(1.f / (1.f + __expf(-L)));
                    p0[j2] = nc0[j2] * s;
                    p1[j2] = nc1[j2] * s;
                    p2[j2] = nc2[j2] * s;
                    p3[j2] = nc3[j2] * s;
                }
                *(f16x8*)(Lsel + no)            = lout;
                *(f16x8*)(Pout + r0)            = p0;
                *(f16x8*)(Pout + r0 + PIX)      = p1;
                *(f16x8*)(Pout + r0 + 2 * PIX)  = p2;
                *(f16x8*)(Pout + r0 + 3 * PIX)  = p3;
            }
            __syncthreads();
        }
    }
}

// Phase A-a: [0,1024) NC = notmF @ Mn^T, [1024,1280) En = emptyF @ Mem^T
__global__ void __launch_bounds__(256, 4) gemm_faA(
    const f16* __restrict__ Mn, const f16* __restrict__ Mem,
    const f16* __restrict__ notmF, const f16* __restrict__ emptyF,
    f16* __restrict__ NC, f16* __restrict__ En) {
    __shared__ __attribute__((aligned(16))) char smem[34816];
    int bi = blockIdx.x;
    if (bi < 1024) {
        run_gemm<0>(bi, 16, 8, smem, notmF, Mn, nullptr, nullptr, nullptr,
                    nullptr, nullptr, NC, PIX);
    } else {
        run_gemm<0>(bi - 1024, 4, 8, smem, emptyF, Mem, nullptr, nullptr, nullptr,
                    nullptr, nullptr, En, PIX);
    }
}

// Phase A-b: stage1 GEMM (eachF @ Me^T) with fused mk_sa -> Lsel, P1
__global__ void __launch_bounds__(256, 4) gemm_faB(
    const f16* __restrict__ Me, const f16* __restrict__ eachF,
    const unsigned char* __restrict__ board, const f16* __restrict__ En,
    const f16* __restrict__ NC, f16* __restrict__ Lsel, f16* __restrict__ P1) {
    __shared__ __attribute__((aligned(16))) char smem[36864];
    run_gemm<2>(blockIdx.x, 16, 8, smem, eachF, Me, board, En, NC,
                Lsel, P1, nullptr, 0);
}

// ---------------------------------------------------------------------------
// Depth GEMM, pure-async, banded + balanced: A = P_d, B = Mn2.
// Vectorized epilogue (loads hoisted): MODE 3 -> Lsel + P_{d+1};
// MODE 4 -> feat = sigmoid. 4 blocks/CU.
// ---------------------------------------------------------------------------
template <int MODE>
__global__ void __launch_bounds__(256, 4) gemm_depth(
    const f16* __restrict__ Pin, const f16* __restrict__ Mn2,
    const unsigned char* __restrict__ board, const f16* __restrict__ NC,
    const f16* __restrict__ En, f16* __restrict__ Lsel,
    f16* __restrict__ Pout, f16* __restrict__ feat) {
    __shared__ __attribute__((aligned(16))) char smem[36864];
    char* smB = smem;
    char* smA = smem + 16384;

    const int tid = threadIdx.x;
    const int wv = tid >> 6, ln = tid & 63;
    const int wm = wv >> 1, wn_ = wv & 1;
    const int lr = ln & 15, lq = ln >> 4;

    int bi = blockIdx.x;
    int xcd = bi & 7, slot = bi >> 3;
    int bx = bx_balanced(slot, 8);
    int by = xcd * 16 + (slot >> 3);
    const int rtile = by * 128, otile = bx * 128;

    int t_lo, t_hi;
    band_range(otile, t_lo, t_hi);

    const f32x4 fz = {0.f, 0.f, 0.f, 0.f};
    f32x4 acc[4][4];
#pragma unroll
    for (int i = 0; i < 4; i++)
#pragma unroll
        for (int j = 0; j < 4; j++) acc[i][j] = fz;

    for (int kt = t_lo; kt <= t_hi; kt++) {
        const int kb = kt * 64;
#pragma unroll
        for (int t = 0; t < 4; t++) {
            int c = (wv * 4 + t) * 64 + ln;
            int row = c >> 3, gcol = (c & 7) ^ (row & 7);
            gld_lds16(Mn2 + (size_t)(otile + row) * 1024 + kb + gcol * 8, smB + c * 16);
            gld_lds16(Pin + (size_t)(rtile + row) * 1024 + kb + gcol * 8, smA + c * 16);
        }
        __syncthreads();

#pragma unroll
        for (int kk = 0; kk < 2; kk++) {
            const int oct = kk * 4 + lq;
            f16x8 af[4], bfr[4];
#pragma unroll
            for (int i = 0; i < 4; i++) {
                int rrow = wm * 64 + i * 16 + lr;
                af[i] = *(const f16x8*)(smA + rrow * 128 + (oct ^ (rrow & 7)) * 16);
            }
#pragma unroll
            for (int j = 0; j < 4; j++) {
                int brow = wn_ * 64 + j * 16 + lr;
                bfr[j] = *(const f16x8*)(smB + brow * 128 + (oct ^ (brow & 7)) * 16);
            }
#pragma unroll
            for (int i = 0; i < 4; i++)
#pragma unroll
                for (int j = 0; j < 4; j++)
                    acc[i][j] = __builtin_amdgcn_mfma_f32_16x16x32_f16(
                        af[i], bfr[j], acc[i][j], 0, 0, 0);
        }
        __syncthreads();
    }

    // ---- vectorized epilogue, loads hoisted above the barrier ----
    float* sAcc = (float*)smem;
#pragma unroll
    for (int h = 0; h < 2; h++) {
        int cell = tid >> 4, cg = tid & 15;
        int rb = rtile + h * 64 + cell * 4;
        int ngl = rb >> 2;
        int o = otile + cg * 8;
        size_t no = (size_t)ngl * PIX + o;
        size_t r0 = (size_t)rb * PIX + o;
        uint64_t bb = *(const uint64_t*)(board + no);
        f16x8 en8 = *(const f16x8*)(En + no);
        f16x8 ls8 = *(const f16x8*)(Lsel + no);
        f16x8 nc0, nc1, nc2, nc3;
        if constexpr (MODE == 3) {
            nc0 = *(const f16x8*)(NC + r0);
            nc1 = *(const f16x8*)(NC + r0 + PIX);
            nc2 = *(const f16x8*)(NC + r0 + 2 * PIX);
            nc3 = *(const f16x8*)(NC + r0 + 3 * PIX);
        }
        if (wm == h) {
#pragma unroll
            for (int i = 0; i < 4; i++) {
                int lrow = i * 16 + lq * 4;
#pragma unroll
                for (int j = 0; j < 4; j++) {
                    int col = wn_ * 64 + j * 16 + lr;
                    f32x4 a = acc[i][j];
#pragma unroll
                    for (int v = 0; v < 4; v++)
                        sAcc[(lrow + v) * 132 + col] = a[v];
                }
            }
        }
        __syncthreads();
        {
            const float* ar = sAcc + cell * 4 * 132 + cg * 8;
            f32x4 arow[4][2];
#pragma unroll
            for (int k = 0; k < 4; k++) {
                arow[k][0] = *(const f32x4*)(ar + k * 132);
                arow[k][1] = *(const f32x4*)(ar + k * 132 + 4);
            }
            if constexpr (MODE == 4) {
                f16x8 s8;
#pragma unroll
                for (int j2 = 0; j2 < 8; j2++) {
                    int c = (int)((bb >> (8 * j2)) & 0xff);
                    float a0 = arow[0][j2 >> 2][j2 & 3];
                    float a1 = arow[1][j2 >> 2][j2 & 3];
                    float a2 = arow[2][j2 >> 2][j2 & 3];
                    float a3 = arow[3][j2 >> 2][j2 & 3];
                    float asel = (c == 1) ? a0 : (c == 2) ? a1 : (c == 3) ? a2 : a3;
                    float L = 0.f;
                    if (c > 0) L = (float)ls8[j2] + (float)en8[j2] + asel;
                    s8[j2] = (f16)(1.f / (1.f + __expf(-L)));
                }
                *(f16x8*)(feat + no) = s8;
            } else {
                f16x8 lout, p0, p1, p2, p3;
#pragma unroll
                for (int j2 = 0; j2 < 8; j2++) {
                    int c = (int)((bb >> (8 * j2)) & 0xff);
                    float a0 = arow[0][j2 >> 2][j2 & 3];
                    float a1 = arow[1][j2 >> 2][j2 & 3];
                    float a2 = arow[2][j2 >> 2][j2 & 3];
                    float a3 = arow[3][j2 >> 2][j2 & 3];
                    float asel = (c == 1) ? a0 : (c == 2) ? a1 : (c == 3) ? a2 : a3;
                    float L = 0.f;
                    if (c > 0) L = (float)ls8[j2] + (float)en8[j2] + asel;
                    lout[j2] = (f16)L;
                    f16 s = (f16)(1.f / (1.f + __expf(-L)));
                    p0[j2] = nc0[j2] * s;
                    p1[j2] = nc1[j2] * s;
                    p2[j2] = nc2[j2] * s;
                    p3[j2] = nc3[j2] * s;
                }
                *(f16x8*)(Lsel + no)           = lout;
                *(f16x8*)(Pout + r0)           = p0;
                *(f16x8*)(Pout + r0 + PIX)     = p1;
                *(f16x8*)(Pout + r0 + 2 * PIX) = p2;
                *(f16x8*)(Pout + r0 + 3 * PIX) = p3;
            }
        }
        __syncthreads();
    }
}

// ---------------------------------------------------------------------------
// MLP: BM=32 / 128 blocks. X1 = leaky(feat@W1b^T); layers 2+3 fused
// in-block via LDS (xs[32][101]; W2 in f16). A-tile = 32x64 f16 = 256
// 16B chunks -> ALL 256 threads stage one chunk (R24 bug: only 128).
// ---------------------------------------------------------------------------
__global__ void __launch_bounds__(256) gemm_mlp_fused(
    const f16* __restrict__ feat, const f16* __restrict__ W1b,
    const float* __restrict__ W2, const float* __restrict__ W3,
    float* __restrict__ out) {
    __shared__ __attribute__((aligned(16))) char smem[47360];
    char* smB = smem;                     // W1b tile 16 KB
    char* smA = smem + 16384;             // feat tile 4 KB

    const int tid = threadIdx.x;
    const int wv = tid >> 6, ln = tid & 63;
    const int wm = wv >> 1, wn_ = wv & 1;
    const int lr = ln & 15, lq = ln >> 4;
    const int rtile = blockIdx.x * 32;             // 128 blocks

    const f32x4 fz = {0.f, 0.f, 0.f, 0.f};
    f32x4 acc[4];
#pragma unroll
    for (int j = 0; j < 4; j++) acc[j] = fz;

    for (int kb = 0; kb < 1024; kb += 64) {
#pragma unroll
        for (int t = 0; t < 4; t++) {
            int c = (wv * 4 + t) * 64 + ln;
            int row = c >> 3, gcol = (c & 7) ^ (row & 7);
            gld_lds16(W1b + (size_t)row * 1024 + kb + gcol * 8, smB + c * 16);
        }
        {   // A tile: 32 rows x 64 k = 256 chunks, one per thread
            int row = tid >> 3, gcol = (tid & 7) ^ (row & 7);
            gld_lds16(feat + (size_t)(rtile + row) * 1024 + kb + gcol * 8,
                      smA + tid * 16);
        }
        __syncthreads();
#pragma unroll
        for (int kk = 0; kk < 2; kk++) {
            const int oct = kk * 4 + lq;
            int rrow = wm * 16 + lr;
            f16x8 af = *(const f16x8*)(smA + rrow * 128 + (oct ^ (rrow & 7)) * 16);
            f16x8 bfr[4];
#pragma unroll
            for (int j = 0; j < 4; j++) {
                int brow = wn_ * 64 + j * 16 + lr;
                bfr[j] = *(const f16x8*)(smB + brow * 128 + (oct ^ (brow & 7)) * 16);
            }
#pragma unroll
            for (int j = 0; j < 4; j++)
                acc[j] = __builtin_amdgcn_mfma_f32_16x16x32_f16(
                    af, bfr[j], acc[j], 0, 0, 0);
        }
        __syncthreads();
    }

    float* xs  = (float*)smem;                     // [32][101]
    f16*   sW2 = (f16*)(smem + 25856);             // [100][100]
    float* sW3 = (float*)(smem + 45856);           // [100]
    float* red = (float*)(smem + 46272);           // [256]
    for (int idx = tid; idx < 10000; idx += 256) sW2[idx] = (f16)W2[idx];
    if (tid < 100) sW3[tid] = W3[tid];

    {
        int rb = wm * 16 + lq * 4;
#pragma unroll
        for (int j = 0; j < 4; j++) {
            int o = wn_ * 64 + j * 16 + lr;
            if (o < 100) {
                f32x4 a = acc[j];
#pragma unroll
                for (int v = 0; v < 4; v++) {
                    float x = a[v];
                    xs[(rb + v) * 101 + o] = x > 0.f ? x : 0.2f * x;
                }
            }
        }
    }
    __syncthreads();
    {
        int nb = tid >> 3, q = tid & 7;            // 32 rows x 8-way j split
        const float* xrow = xs + nb * 101;
        float partial = 0.f;
        for (int jj = 0; jj < 13; jj++) {
            int j = q + jj * 8;
            if (j < 100) {
                const f16* w2r = sW2 + j * 100;
                float a2 = 0.f;
#pragma unroll
                for (int i = 0; i < 100; i++) a2 += (float)w2r[i] * xrow[i];
                partial += sW3[j] * (a2 > 0.f ? a2 : 0.2f * a2);
            }
        }
        red[tid] = partial;
        __syncthreads();
        if (q == 0) {
            float s = 0.f;
#pragma unroll
            for (int k = 0; k < 8; k++) s += red[tid + k];
            out[rtile + nb] = s;
        }
    }
}

extern "C" void kernel_launch(void* const* d_in, const int* in_sizes, int n_in,
                              void* d_out, int out_size, void* d_ws, size_t ws_size,
                              hipStream_t stream) {
    (void)in_sizes; (void)n_in; (void)out_size; (void)ws_size;
    const int*   dots   = (const int*)d_in[0];
    const float* w_each = (const float*)d_in[1];
    const float* w_not  = (const float*)d_in[2];
    const float* w_not2 = (const float*)d_in[3];
    const float* w_emp  = (const float*)d_in[4];
    const float* W1 = (const float*)d_in[5];
    const float* W2 = (const float*)d_in[6];
    const float* W3 = (const float*)d_in[7];
    float* out = (float*)d_out;

    char* ws = (char*)d_ws;
    size_t off = 0;
    auto alloc = [&](size_t bytes) -> char* {
        char* p = ws + off;
        off += (bytes + 255) & ~(size_t)255;
        return p;
    };
    f16* Me    = (f16*)alloc((size_t)PIX * PIX * 2);
    f16* Mn    = (f16*)alloc((size_t)PIX * PIX * 2);
    f16* Mn2   = (f16*)alloc((size_t)PIX * PIX * 2);
    f16* Mem   = (f16*)alloc((size_t)PIX * PIX * 2);
    f16* W1b   = (f16*)alloc((size_t)128 * PIX * 2);
    unsigned char* board = (unsigned char*)alloc((size_t)NB * PIX);
    f16* eachF = (f16*)alloc((size_t)MR * PIX * 2);   // 32 MB, dead after faB
    f16* notmF = (f16*)alloc((size_t)MR * PIX * 2);   // 32 MB, dead after faA
    f16* emptyF= (f16*)alloc((size_t)NB * PIX * 2);   // 8 MB
    f16* NC    = (f16*)alloc((size_t)MR * PIX * 2);   // 32 MB
    f16* En    = (f16*)alloc((size_t)NB * PIX * 2);
    f16* Lsel  = (f16*)alloc((size_t)NB * PIX * 2);
    f16* feat  = (f16*)alloc((size_t)NB * PIX * 2);
    // P ping-pong buffers alias dead mask regions (32 MB each)
    f16* Pa = notmF;   // written by faB (notmF dead after faA)
    f16* Pb = eachF;   // written by depth1 (eachF dead after faB)

    dim3 blk(256);
    // precompute: conv mats + W1 pad + board transpose + mask expansion
    build_all<<<5632, blk, 0, stream>>>(w_each, w_not, w_not2, w_emp, W1, dots,
                                        Me, Mn, Mn2, Mem, W1b, board,
                                        eachF, notmF, emptyF);
    // Phase A-a: NC + En
    gemm_faA<<<1280, blk, 0, stream>>>(Mn, Mem, notmF, emptyF, NC, En);
    // Phase A-b: stage1 with fused mk_sa -> Lsel, P1 (into Pa)
    gemm_faB<<<1024, blk, 0, stream>>>(Me, eachF, board, En, NC, Lsel, Pa);
    // depth 1..3: pure-async banded balanced GEMM; epilogue emits P_{d+1}
    gemm_depth<3><<<1024, blk, 0, stream>>>(Pa, Mn2, board, NC, En, Lsel, Pb, nullptr);
    gemm_depth<3><<<1024, blk, 0, stream>>>(Pb, Mn2, board, NC, En, Lsel, Pa, nullptr);
    gemm_depth<3><<<1024, blk, 0, stream>>>(Pa, Mn2, board, NC, En, Lsel, Pb, nullptr);
    // depth 4 -> feat
    gemm_depth<4><<<1024, blk, 0, stream>>>(Pb, Mn2, board, NC, En, Lsel, nullptr, feat);
    // MLP 1+2+3 fused
    gemm_mlp_fused<<<128, blk, 0, stream>>>(feat, W1b, W2, W3, out);
}

// Round 11
// 363.127 us; speedup vs baseline: 1.0212x; 1.0212x over previous
//
#include <hip/hip_runtime.h>
#include <cstdint>
#include <cstddef>

// ---------------------------------------------------------------------------
// NN_each_LN_exp: 33x33 SAME convs on 32x32 maps = dense 1024x1024 linear
// operators -> f16 MFMA GEMMs with fused epilogues. Row layout r = n*4+k.
// R26 = R23 GEMM path verbatim (364.7us best) + R25's fixed MLP (BM=32 /
// 128 blocks). R24/R25's bx_balanced flip REVERTED (cost ~5%/dispatch:
// broke same-bx L2 row-panel locality; the CU-skew it targeted is absorbed
// by the 1024-block pool). Epilogue-load hoist REVERTED (compiler sank it;
// VGPR stayed 64 -> no-op).
// Session ledger:
//  - 128x128 tile / 4 waves / pure-async m97 staging: measured optimum
//  - 8-phase 256^2: neutral at K=1024 (R17); chain fusion: regress (R18)
//  - vector epilogues (R19), mask expansion + (256,4) (R20), band (R21)
//  - s-fold (A = NC*s in K-loop): REGRESSION x2 (R16,R22). DO NOT RETRY.
//  - bx balance flip: REGRESSION (R25). Keep plain bx = slot % nx.
// ---------------------------------------------------------------------------

typedef _Float16 f16;
typedef __attribute__((ext_vector_type(8))) _Float16 f16x8;
typedef __attribute__((ext_vector_type(4))) float f32x4;

#define NB   4096
#define PIX  1024
#define MR   (NB * 4)

__device__ __forceinline__ void gld_lds16(const void* g, void* l) {
    __builtin_amdgcn_global_load_lds(
        (const __attribute__((address_space(1))) void*)g,
        (__attribute__((address_space(3))) void*)l, 16, 0, 0);
}

// conv band: K-tile t (64 inputs = 2 in-rows) vs o-tile starting out-row i0
__device__ __forceinline__ void band_range(int otile, int& t_lo, int& t_hi) {
    int i0 = otile >> 5;
    t_lo = (i0 > 16) ? ((i0 - 16) >> 1) : 0;
    t_hi = (i0 + 19) >> 1;
    if (t_hi > 15) t_hi = 15;
}

// Merged builds: [0,4096) conv mats, [4096,4608) W1 pad,
// [4608,5632) board transpose + mask expansion (from LDS tile)
__global__ void build_all(const float* __restrict__ we, const float* __restrict__ wn,
                          const float* __restrict__ wn2, const float* __restrict__ wem,
                          const float* __restrict__ W1, const int* __restrict__ dots,
                          f16* __restrict__ Me, f16* __restrict__ Mn,
                          f16* __restrict__ Mn2, f16* __restrict__ Mem,
                          f16* __restrict__ W1b, unsigned char* __restrict__ board,
                          f16* __restrict__ eachF, f16* __restrict__ notmF,
                          f16* __restrict__ emptyF) {
    __shared__ unsigned char tile[64][68];
    int bi = blockIdx.x, t = threadIdx.x;
    if (bi < 4096) {
        int idx = bi * 256 + t;
        int o = idx >> 10, in = idx & 1023;
        int i = o >> 5, j = o & 31, a = in >> 5, b = in & 31;
        int u = a - i + 16, v = b - j + 16;
        bool ok = (u >= 0) && (u < 33) && (v >= 0) && (v < 33);
        int w = u * 33 + v;
        float ve = 0.f, vn = 0.f, vn2 = 0.f, vem = 0.f;
        if (ok) { ve = we[w]; vn = wn[w]; vn2 = wn2[w]; vem = wem[w]; }
        Me[idx]  = (f16)ve;
        Mn[idx]  = (f16)vn;
        Mn2[idx] = (f16)vn2;
        Mem[idx] = (f16)vem;
    } else if (bi < 4608) {
        int idx = (bi - 4096) * 256 + t;
        int j = idx >> 10, i = idx & 1023;
        W1b[idx] = (f16)(j < 100 ? W1[j * 1024 + i] : 0.f);
    } else {
        int bb = bi - 4608;
        int bp = bb & 15, bn = bb >> 4;
        int p0 = bp * 64, n0 = bn * 64;
        int ln = t & 63, lp = t >> 6;
#pragma unroll
        for (int j = 0; j < 16; j++) {
            int p = lp * 16 + j;
            tile[p][ln] = (unsigned char)dots[(size_t)(p0 + p) * 4096 + n0 + ln];
        }
        __syncthreads();
#pragma unroll
        for (int j = 0; j < 16; j++) {
            int n = lp * 16 + j;
            unsigned char c = tile[ln][n];
            size_t nrow = (size_t)(n0 + n);
            board[nrow * 1024 + p0 + ln] = c;
            emptyF[nrow * PIX + p0 + ln] = (c == 0) ? (f16)1.f : (f16)0.f;
            size_t r0 = (nrow * 4) * PIX + p0 + ln;
#pragma unroll
            for (int k = 0; k < 4; k++) {
                unsigned char k1 = (unsigned char)(k + 1);
                eachF[r0 + (size_t)k * PIX] = (c == k1) ? (f16)1.f : (f16)0.f;
                notmF[r0 + (size_t)k * PIX] =
                    (c != 0 && c != k1) ? (f16)1.f : (f16)0.f;
            }
        }
    }
}

// ---------------------------------------------------------------------------
// Generic GEMM body: BM=BN=128, BK=64, 4 waves as 2x2, 16x16x32 MFMA,
// XOR-swizzled chunks, pure-async gld_lds staging, banded K-loop.
// MODE: 0 f16-out ldo (LDS-transposed vector store)
//       2 stage1 fused-mk_sa (vector epilogue): L0 = asel + En - NCsel;
//         Lsel=L0(f16); Pout[4n+k] = NC[4n+k] * sigmoid(L0)
// ---------------------------------------------------------------------------
template <int MODE>
__device__ __forceinline__ void run_gemm(
    int bjob, int ypx, int nx, char* smem,
    const f16* __restrict__ X, const f16* __restrict__ B,
    const unsigned char* __restrict__ board, const f16* __restrict__ En,
    const f16* __restrict__ NCs, f16* __restrict__ Lsel,
    f16* __restrict__ Pout, f16* __restrict__ outB, int ldo) {
    char* smB = smem;                              // 16 KB
    char* smA = smem + 16384;

    const int tid = threadIdx.x;
    const int wv = tid >> 6, ln = tid & 63;
    const int wm = wv >> 1, wn_ = wv & 1;
    const int lr = ln & 15, lq = ln >> 4;

    int xcd = bjob & 7, slot = bjob >> 3;
    int bx = slot % nx;
    int by = xcd * ypx + slot / nx;
    const int rtile = by * 128, otile = bx * 128;

    int t_lo, t_hi;
    band_range(otile, t_lo, t_hi);

    const f32x4 fz = {0.f, 0.f, 0.f, 0.f};
    f32x4 acc[4][4];
#pragma unroll
    for (int i = 0; i < 4; i++)
#pragma unroll
        for (int j = 0; j < 4; j++) acc[i][j] = fz;

    for (int kt = t_lo; kt <= t_hi; kt++) {
        const int kb = kt * 64;
#pragma unroll
        for (int t = 0; t < 4; t++) {
            int c = (wv * 4 + t) * 64 + ln;
            int row = c >> 3, gcol = (c & 7) ^ (row & 7);
            gld_lds16(B + (size_t)(otile + row) * 1024 + kb + gcol * 8, smB + c * 16);
            gld_lds16(X + (size_t)(rtile + row) * 1024 + kb + gcol * 8, smA + c * 16);
        }
        __syncthreads();

#pragma unroll
        for (int kk = 0; kk < 2; kk++) {
            const int oct = kk * 4 + lq;
            f16x8 af[4], bfr[4];
#pragma unroll
            for (int i = 0; i < 4; i++) {
                int rrow = wm * 64 + i * 16 + lr;
                af[i] = *(const f16x8*)(smA + rrow * 128 + (oct ^ (rrow & 7)) * 16);
            }
#pragma unroll
            for (int j = 0; j < 4; j++) {
                int brow = wn_ * 64 + j * 16 + lr;
                bfr[j] = *(const f16x8*)(smB + brow * 128 + (oct ^ (brow & 7)) * 16);
            }
#pragma unroll
            for (int i = 0; i < 4; i++)
#pragma unroll
                for (int j = 0; j < 4; j++)
                    acc[i][j] = __builtin_amdgcn_mfma_f32_16x16x32_f16(
                        af[i], bfr[j], acc[i][j], 0, 0, 0);
        }
        __syncthreads();
    }

    // ---- vectorized epilogue (staging LDS is dead past here) ----
    if constexpr (MODE == 0) {
        f16* sT = (f16*)smem;
#pragma unroll
        for (int i = 0; i < 4; i++) {
            int rb = wm * 64 + i * 16 + lq * 4;
#pragma unroll
            for (int j = 0; j < 4; j++) {
                int col = wn_ * 64 + j * 16 + lr;
                f32x4 a = acc[i][j];
#pragma unroll
                for (int v = 0; v < 4; v++)
                    sT[(rb + v) * 136 + col] = (f16)a[v];
            }
        }
        __syncthreads();
#pragma unroll
        for (int it = 0; it < 8; it++) {
            int row = it * 16 + (tid >> 4), cg = tid & 15;
            f16x8 vv = *(const f16x8*)(sT + row * 136 + cg * 8);
            *(f16x8*)(outB + (size_t)(rtile + row) * ldo + otile + cg * 8) = vv;
        }
    } else {
        // f32 acc halves [64][132]; asel stays f32 (R15 rounding)
        float* sAcc = (float*)smem;
#pragma unroll
        for (int h = 0; h < 2; h++) {
            if (wm == h) {
#pragma unroll
                for (int i = 0; i < 4; i++) {
                    int lrow = i * 16 + lq * 4;
#pragma unroll
                    for (int j = 0; j < 4; j++) {
                        int col = wn_ * 64 + j * 16 + lr;
                        f32x4 a = acc[i][j];
#pragma unroll
                        for (int v = 0; v < 4; v++)
                            sAcc[(lrow + v) * 132 + col] = a[v];
                    }
                }
            }
            __syncthreads();
            {
                int cell = tid >> 4, cg = tid & 15;
                int rb = rtile + h * 64 + cell * 4;        // global row base
                int ngl = rb >> 2;
                int o = otile + cg * 8;
                size_t no = (size_t)ngl * PIX + o;
                uint64_t bb = *(const uint64_t*)(board + no);
                f16x8 en8 = *(const f16x8*)(En + no);
                size_t r0 = (size_t)rb * PIX + o;
                f16x8 nc0 = *(const f16x8*)(NCs + r0);
                f16x8 nc1 = *(const f16x8*)(NCs + r0 + PIX);
                f16x8 nc2 = *(const f16x8*)(NCs + r0 + 2 * PIX);
                f16x8 nc3 = *(const f16x8*)(NCs + r0 + 3 * PIX);
                const float* ar = sAcc + cell * 4 * 132 + cg * 8;
                f32x4 arow[4][2];
#pragma unroll
                for (int k = 0; k < 4; k++) {
                    arow[k][0] = *(const f32x4*)(ar + k * 132);
                    arow[k][1] = *(const f32x4*)(ar + k * 132 + 4);
                }
                f16x8 lout, p0, p1, p2, p3;
#pragma unroll
                for (int j2 = 0; j2 < 8; j2++) {
                    int c = (int)((bb >> (8 * j2)) & 0xff);
                    float a0 = arow[0][j2 >> 2][j2 & 3];
                    float a1 = arow[1][j2 >> 2][j2 & 3];
                    float a2 = arow[2][j2 >> 2][j2 & 3];
                    float a3 = arow[3][j2 >> 2][j2 & 3];
                    float asel = (c == 1) ? a0 : (c == 2) ? a1 : (c == 3) ? a2 : a3;
                    float L = 0.f;
                    if (c > 0) {
                        float ncsel = (float)((c == 1) ? nc0[j2] : (c == 2) ? nc1[j2]
                                            : (c == 3) ? nc2[j2] : nc3[j2]);
                        L = asel + (float)en8[j2] - ncsel;
                    }
                    lout[j2] = (f16)L;
                    f16 s = (f16)(1.f / (1.f + __expf(-L)));
                    p0[j2] = nc0[j2] * s;
                    p1[j2] = nc1[j2] * s;
                    p2[j2] = nc2[j2] * s;
                    p3[j2] = nc3[j2] * s;
                }
                *(f16x8*)(Lsel + no)            = lout;
                *(f16x8*)(Pout + r0)            = p0;
                *(f16x8*)(Pout + r0 + PIX)      = p1;
                *(f16x8*)(Pout + r0 + 2 * PIX)  = p2;
                *(f16x8*)(Pout + r0 + 3 * PIX)  = p3;
            }
            __syncthreads();
        }
    }
}

// Phase A-a: [0,1024) NC = notmF @ Mn^T, [1024,1280) En = emptyF @ Mem^T
__global__ void __launch_bounds__(256, 4) gemm_faA(
    const f16* __restrict__ Mn, const f16* __restrict__ Mem,
    const f16* __restrict__ notmF, const f16* __restrict__ emptyF,
    f16* __restrict__ NC, f16* __restrict__ En) {
    __shared__ __attribute__((aligned(16))) char smem[34816];
    int bi = blockIdx.x;
    if (bi < 1024) {
        run_gemm<0>(bi, 16, 8, smem, notmF, Mn, nullptr, nullptr, nullptr,
                    nullptr, nullptr, NC, PIX);
    } else {
        run_gemm<0>(bi - 1024, 4, 8, smem, emptyF, Mem, nullptr, nullptr, nullptr,
                    nullptr, nullptr, En, PIX);
    }
}

// Phase A-b: stage1 GEMM (eachF @ Me^T) with fused mk_sa -> Lsel, P1
__global__ void __launch_bounds__(256, 4) gemm_faB(
    const f16* __restrict__ Me, const f16* __restrict__ eachF,
    const unsigned char* __restrict__ board, const f16* __restrict__ En,
    const f16* __restrict__ NC, f16* __restrict__ Lsel, f16* __restrict__ P1) {
    __shared__ __attribute__((aligned(16))) char smem[36864];
    run_gemm<2>(blockIdx.x, 16, 8, smem, eachF, Me, board, En, NC,
                Lsel, P1, nullptr, 0);
}

// ---------------------------------------------------------------------------
// Depth GEMM, pure-async (m97 structure), banded K-loop: A = P_d, B = Mn2.
// Vectorized epilogue: MODE 3 -> Lsel + P_{d+1}; MODE 4 -> feat = sigmoid.
// 4 blocks/CU (m114 cross-block overlap).
// ---------------------------------------------------------------------------
template <int MODE>
__global__ void __launch_bounds__(256, 4) gemm_depth(
    const f16* __restrict__ Pin, const f16* __restrict__ Mn2,
    const unsigned char* __restrict__ board, const f16* __restrict__ NC,
    const f16* __restrict__ En, f16* __restrict__ Lsel,
    f16* __restrict__ Pout, f16* __restrict__ feat) {
    __shared__ __attribute__((aligned(16))) char smem[36864];
    char* smB = smem;
    char* smA = smem + 16384;

    const int tid = threadIdx.x;
    const int wv = tid >> 6, ln = tid & 63;
    const int wm = wv >> 1, wn_ = wv & 1;
    const int lr = ln & 15, lq = ln >> 4;

    int bi = blockIdx.x;
    int xcd = bi & 7, slot = bi >> 3;
    int bx = slot & 7;
    int by = xcd * 16 + (slot >> 3);
    const int rtile = by * 128, otile = bx * 128;

    int t_lo, t_hi;
    band_range(otile, t_lo, t_hi);

    const f32x4 fz = {0.f, 0.f, 0.f, 0.f};
    f32x4 acc[4][4];
#pragma unroll
    for (int i = 0; i < 4; i++)
#pragma unroll
        for (int j = 0; j < 4; j++) acc[i][j] = fz;

    for (int kt = t_lo; kt <= t_hi; kt++) {
        const int kb = kt * 64;
#pragma unroll
        for (int t = 0; t < 4; t++) {
            int c = (wv * 4 + t) * 64 + ln;
            int row = c >> 3, gcol = (c & 7) ^ (row & 7);
            gld_lds16(Mn2 + (size_t)(otile + row) * 1024 + kb + gcol * 8, smB + c * 16);
            gld_lds16(Pin + (size_t)(rtile + row) * 1024 + kb + gcol * 8, smA + c * 16);
        }
        __syncthreads();

#pragma unroll
        for (int kk = 0; kk < 2; kk++) {
            const int oct = kk * 4 + lq;
            f16x8 af[4], bfr[4];
#pragma unroll
            for (int i = 0; i < 4; i++) {
                int rrow = wm * 64 + i * 16 + lr;
                af[i] = *(const f16x8*)(smA + rrow * 128 + (oct ^ (rrow & 7)) * 16);
            }
#pragma unroll
            for (int j = 0; j < 4; j++) {
                int brow = wn_ * 64 + j * 16 + lr;
                bfr[j] = *(const f16x8*)(smB + brow * 128 + (oct ^ (brow & 7)) * 16);
            }
#pragma unroll
            for (int i = 0; i < 4; i++)
#pragma unroll
                for (int j = 0; j < 4; j++)
                    acc[i][j] = __builtin_amdgcn_mfma_f32_16x16x32_f16(
                        af[i], bfr[j], acc[i][j], 0, 0, 0);
        }
        __syncthreads();
    }

    // ---- vectorized epilogue (two f32 halves in dead staging LDS) ----
    float* sAcc = (float*)smem;
#pragma unroll
    for (int h = 0; h < 2; h++) {
        if (wm == h) {
#pragma unroll
            for (int i = 0; i < 4; i++) {
                int lrow = i * 16 + lq * 4;
#pragma unroll
                for (int j = 0; j < 4; j++) {
                    int col = wn_ * 64 + j * 16 + lr;
                    f32x4 a = acc[i][j];
#pragma unroll
                    for (int v = 0; v < 4; v++)
                        sAcc[(lrow + v) * 132 + col] = a[v];
                }
            }
        }
        __syncthreads();
        {
            int cell = tid >> 4, cg = tid & 15;
            int rb = rtile + h * 64 + cell * 4;
            int ngl = rb >> 2;
            int o = otile + cg * 8;
            size_t no = (size_t)ngl * PIX + o;
            uint64_t bb = *(const uint64_t*)(board + no);
            f16x8 en8 = *(const f16x8*)(En + no);
            f16x8 ls8 = *(const f16x8*)(Lsel + no);
            const float* ar = sAcc + cell * 4 * 132 + cg * 8;
            f32x4 arow[4][2];
#pragma unroll
            for (int k = 0; k < 4; k++) {
                arow[k][0] = *(const f32x4*)(ar + k * 132);
                arow[k][1] = *(const f32x4*)(ar + k * 132 + 4);
            }
            if constexpr (MODE == 4) {
                f16x8 s8;
#pragma unroll
                for (int j2 = 0; j2 < 8; j2++) {
                    int c = (int)((bb >> (8 * j2)) & 0xff);
                    float a0 = arow[0][j2 >> 2][j2 & 3];
                    float a1 = arow[1][j2 >> 2][j2 & 3];
                    float a2 = arow[2][j2 >> 2][j2 & 3];
                    float a3 = arow[3][j2 >> 2][j2 & 3];
                    float asel = (c == 1) ? a0 : (c == 2) ? a1 : (c == 3) ? a2 : a3;
                    float L = 0.f;
                    if (c > 0) L = (float)ls8[j2] + (float)en8[j2] + asel;
                    s8[j2] = (f16)(1.f / (1.f + __expf(-L)));
                }
                *(f16x8*)(feat + no) = s8;
            } else {
                size_t r0 = (size_t)rb * PIX + o;
                f16x8 nc0 = *(const f16x8*)(NC + r0);
                f16x8 nc1 = *(const f16x8*)(NC + r0 + PIX);
                f16x8 nc2 = *(const f16x8*)(NC + r0 + 2 * PIX);
                f16x8 nc3 = *(const f16x8*)(NC + r0 + 3 * PIX);
                f16x8 lout, p0, p1, p2, p3;
#pragma unroll
                for (int j2 = 0; j2 < 8; j2++) {
                    int c = (int)((bb >> (8 * j2)) & 0xff);
                    float a0 = arow[0][j2 >> 2][j2 & 3];
                    float a1 = arow[1][j2 >> 2][j2 & 3];
                    float a2 = arow[2][j2 >> 2][j2 & 3];
                    float a3 = arow[3][j2 >> 2][j2 & 3];
                    float asel = (c == 1) ? a0 : (c == 2) ? a1 : (c == 3) ? a2 : a3;
                    float L = 0.f;
                    if (c > 0) L = (float)ls8[j2] + (float)en8[j2] + asel;
                    lout[j2] = (f16)L;
                    f16 s = (f16)(1.f / (1.f + __expf(-L)));
                    p0[j2] = nc0[j2] * s;
                    p1[j2] = nc1[j2] * s;
                    p2[j2] = nc2[j2] * s;
                    p3[j2] = nc3[j2] * s;
                }
                *(f16x8*)(Lsel + no)           = lout;
                *(f16x8*)(Pout + r0)           = p0;
                *(f16x8*)(Pout + r0 + PIX)     = p1;
                *(f16x8*)(Pout + r0 + 2 * PIX) = p2;
                *(f16x8*)(Pout + r0 + 3 * PIX) = p3;
            }
        }
        __syncthreads();
    }
}

// ---------------------------------------------------------------------------
// MLP: BM=32 / 128 blocks. X1 = leaky(feat@W1b^T); layers 2+3 fused
// in-block via LDS (xs[32][101]; W2 in f16). A-tile = 32x64 f16 = 256
// 16B chunks, one per thread.
// ---------------------------------------------------------------------------
__global__ void __launch_bounds__(256) gemm_mlp_fused(
    const f16* __restrict__ feat, const f16* __restrict__ W1b,
    const float* __restrict__ W2, const float* __restrict__ W3,
    float* __restrict__ out) {
    __shared__ __attribute__((aligned(16))) char smem[47360];
    char* smB = smem;                     // W1b tile 16 KB
    char* smA = smem + 16384;             // feat tile 4 KB

    const int tid = threadIdx.x;
    const int wv = tid >> 6, ln = tid & 63;
    const int wm = wv >> 1, wn_ = wv & 1;
    const int lr = ln & 15, lq = ln >> 4;
    const int rtile = blockIdx.x * 32;             // 128 blocks

    const f32x4 fz = {0.f, 0.f, 0.f, 0.f};
    f32x4 acc[4];
#pragma unroll
    for (int j = 0; j < 4; j++) acc[j] = fz;

    for (int kb = 0; kb < 1024; kb += 64) {
#pragma unroll
        for (int t = 0; t < 4; t++) {
            int c = (wv * 4 + t) * 64 + ln;
            int row = c >> 3, gcol = (c & 7) ^ (row & 7);
            gld_lds16(W1b + (size_t)row * 1024 + kb + gcol * 8, smB + c * 16);
        }
        {   // A tile: 32 rows x 64 k = 256 chunks, one per thread
            int row = tid >> 3, gcol = (tid & 7) ^ (row & 7);
            gld_lds16(feat + (size_t)(rtile + row) * 1024 + kb + gcol * 8,
                      smA + tid * 16);
        }
        __syncthreads();
#pragma unroll
        for (int kk = 0; kk < 2; kk++) {
            const int oct = kk * 4 + lq;
            int rrow = wm * 16 + lr;
            f16x8 af = *(const f16x8*)(smA + rrow * 128 + (oct ^ (rrow & 7)) * 16);
            f16x8 bfr[4];
#pragma unroll
            for (int j = 0; j < 4; j++) {
                int brow = wn_ * 64 + j * 16 + lr;
                bfr[j] = *(const f16x8*)(smB + brow * 128 + (oct ^ (brow & 7)) * 16);
            }
#pragma unroll
            for (int j = 0; j < 4; j++)
                acc[j] = __builtin_amdgcn_mfma_f32_16x16x32_f16(
                    af, bfr[j], acc[j], 0, 0, 0);
        }
        __syncthreads();
    }

    float* xs  = (float*)smem;                     // [32][101]
    f16*   sW2 = (f16*)(smem + 25856);             // [100][100]
    float* sW3 = (float*)(smem + 45856);           // [100]
    float* red = (float*)(smem + 46272);           // [256]
    for (int idx = tid; idx < 10000; idx += 256) sW2[idx] = (f16)W2[idx];
    if (tid < 100) sW3[tid] = W3[tid];

    {
        int rb = wm * 16 + lq * 4;
#pragma unroll
        for (int j = 0; j < 4; j++) {
            int o = wn_ * 64 + j * 16 + lr;
            if (o < 100) {
                f32x4 a = acc[j];
#pragma unroll
                for (int v = 0; v < 4; v++) {
                    float x = a[v];
                    xs[(rb + v) * 101 + o] = x > 0.f ? x : 0.2f * x;
                }
            }
        }
    }
    __syncthreads();
    {
        int nb = tid >> 3, q = tid & 7;            // 32 rows x 8-way j split
        const float* xrow = xs + nb * 101;
        float partial = 0.f;
        for (int jj = 0; jj < 13; jj++) {
            int j = q + jj * 8;
            if (j < 100) {
                const f16* w2r = sW2 + j * 100;
                float a2 = 0.f;
#pragma unroll
                for (int i = 0; i < 100; i++) a2 += (float)w2r[i] * xrow[i];
                partial += sW3[j] * (a2 > 0.f ? a2 : 0.2f * a2);
            }
        }
        red[tid] = partial;
        __syncthreads();
        if (q == 0) {
            float s = 0.f;
#pragma unroll
            for (int k = 0; k < 8; k++) s += red[tid + k];
            out[rtile + nb] = s;
        }
    }
}

extern "C" void kernel_launch(void* const* d_in, const int* in_sizes, int n_in,
                              void* d_out, int out_size, void* d_ws, size_t ws_size,
                              hipStream_t stream) {
    (void)in_sizes; (void)n_in; (void)out_size; (void)ws_size;
    const int*   dots   = (const int*)d_in[0];
    const float* w_each = (const float*)d_in[1];
    const float* w_not  = (const float*)d_in[2];
    const float* w_not2 = (const float*)d_in[3];
    const float* w_emp  = (const float*)d_in[4];
    const float* W1 = (const float*)d_in[5];
    const float* W2 = (const float*)d_in[6];
    const float* W3 = (const float*)d_in[7];
    float* out = (float*)d_out;

    char* ws = (char*)d_ws;
    size_t off = 0;
    auto alloc = [&](size_t bytes) -> char* {
        char* p = ws + off;
        off += (bytes + 255) & ~(size_t)255;
        return p;
    };
    f16* Me    = (f16*)alloc((size_t)PIX * PIX * 2);
    f16* Mn    = (f16*)alloc((size_t)PIX * PIX * 2);
    f16* Mn2   = (f16*)alloc((size_t)PIX * PIX * 2);
    f16* Mem   = (f16*)alloc((size_t)PIX * PIX * 2);
    f16* W1b   = (f16*)alloc((size_t)128 * PIX * 2);
    unsigned char* board = (unsigned char*)alloc((size_t)NB * PIX);
    f16* eachF = (f16*)alloc((size_t)MR * PIX * 2);   // 32 MB, dead after faB
    f16* notmF = (f16*)alloc((size_t)MR * PIX * 2);   // 32 MB, dead after faA
    f16* emptyF= (f16*)alloc((size_t)NB * PIX * 2);   // 8 MB
    f16* NC    = (f16*)alloc((size_t)MR * PIX * 2);   // 32 MB
    f16* En    = (f16*)alloc((size_t)NB * PIX * 2);
    f16* Lsel  = (f16*)alloc((size_t)NB * PIX * 2);
    f16* feat  = (f16*)alloc((size_t)NB * PIX * 2);
    // P ping-pong buffers alias dead mask regions (32 MB each)
    f16* Pa = notmF;   // written by faB (notmF dead after faA)
    f16* Pb = eachF;   // written by depth1 (eachF dead after faB)

    dim3 blk(256);
    // precompute: conv mats + W1 pad + board transpose + mask expansion
    build_all<<<5632, blk, 0, stream>>>(w_each, w_not, w_not2, w_emp, W1, dots,
                                        Me, Mn, Mn2, Mem, W1b, board,
                                        eachF, notmF, emptyF);
    // Phase A-a: NC + En
    gemm_faA<<<1280, blk, 0, stream>>>(Mn, Mem, notmF, emptyF, NC, En);
    // Phase A-b: stage1 with fused mk_sa -> Lsel, P1 (into Pa)
    gemm_faB<<<1024, blk, 0, stream>>>(Me, eachF, board, En, NC, Lsel, Pa);
    // depth 1..3: pure-async banded GEMM; epilogue emits P_{d+1}
    gemm_depth<3><<<1024, blk, 0, stream>>>(Pa, Mn2, board, NC, En, Lsel, Pb, nullptr);
    gemm_depth<3><<<1024, blk, 0, stream>>>(Pb, Mn2, board, NC, En, Lsel, Pa, nullptr);
    gemm_depth<3><<<1024, blk, 0, stream>>>(Pa, Mn2, board, NC, En, Lsel, Pb, nullptr);
    // depth 4 -> feat
    gemm_depth<4><<<1024, blk, 0, stream>>>(Pb, Mn2, board, NC, En, Lsel, nullptr, feat);
    // MLP 1+2+3 fused
    gemm_mlp_fused<<<128, blk, 0, stream>>>(feat, W1b, W2, W3, out);
}